// Round 9
// baseline (287.996 us; speedup 1.0000x reference)
//
#include <hip/hip_runtime.h>
#include <hip/hip_bf16.h>

#define EMBED 256
#define HEADS 8
#define BATCH 8
#define SEQ   1024
#define NROWS 8192

typedef __attribute__((ext_vector_type(8))) short short8;     // 8 bf16
typedef __attribute__((ext_vector_type(8))) _Float16 half8;   // 8 fp16
typedef __attribute__((ext_vector_type(4))) float f32x4;
typedef unsigned int  uint;
typedef unsigned short ushort;

#define QE   ((size_t)2097152)   /* per-head elems: 8192*256 */

__device__ __forceinline__ ushort f2bf(float f) {
    union { __hip_bfloat16 b; ushort u; } cv; cv.b = __float2bfloat16(f); return cv.u;
}
__device__ __forceinline__ float bf2f(ushort s) {
    union { ushort u; __hip_bfloat16 b; } cv; cv.u = s; return __bfloat162float(cv.b);
}
__device__ __forceinline__ ushort f2h(float f) {
    union { _Float16 h; ushort u; } cv; cv.h = (_Float16)f; return cv.u;
}

// ---------------------------------------------------------------------------
// K0a: X hi/lo bf16 split (float4-vectorized). n4 = elems/4.
// ---------------------------------------------------------------------------
__global__ __launch_bounds__(256) void split_bf16(
    const float* __restrict__ src, ushort* __restrict__ dh,
    ushort* __restrict__ dl, int n4)
{
    const int i = blockIdx.x * 256 + threadIdx.x;
    if (i >= n4) return;
    const float4 v = ((const float4*)src)[i];
    const float vv[4] = {v.x, v.y, v.z, v.w};
    uint hp[4], lp[4];
#pragma unroll
    for (int j = 0; j < 4; ++j) {
        const ushort hb = f2bf(vv[j]);
        hp[j] = hb;
        lp[j] = f2bf(vv[j] - bf2f(hb));
    }
    uint2 H, L;
    H.x = hp[0] | (hp[1] << 16); H.y = hp[2] | (hp[3] << 16);
    L.x = lp[0] | (lp[1] << 16); L.y = lp[2] | (lp[3] << 16);
    ((uint2*)dh)[i] = H;
    ((uint2*)dl)[i] = L;
}

// K0b: weight prep. Regions 0..2 (Wq,Wk,Wv): bf16 hi/lo split.
// Region 3 (Wo): fp16 single.
__global__ __launch_bounds__(256) void split_weights(
    const float* __restrict__ Wq, const float* __restrict__ Wk,
    const float* __restrict__ Wv, const float* __restrict__ Wo,
    ushort* __restrict__ Wqkh, ushort* __restrict__ Wqkl,
    ushort* __restrict__ Wvh,  ushort* __restrict__ Wvl,
    ushort* __restrict__ Wof)
{
    const int blk = blockIdx.x;
    const int region = blk >> 9;            // 0..3
    const int i = (blk & 511) * 256 + threadIdx.x;   // < 131072 float4s
    if (region == 3) {
        const float4 v = ((const float4*)Wo)[i];
        uint2 P;
        P.x = (uint)f2h(v.x) | ((uint)f2h(v.y) << 16);
        P.y = (uint)f2h(v.z) | ((uint)f2h(v.w) << 16);
        ((uint2*)Wof)[i] = P;
        return;
    }
    const float* src; ushort *dh, *dl;
    if (region == 0)      { src = Wq; dh = Wqkh;          dl = Wqkl; }
    else if (region == 1) { src = Wk; dh = Wqkh + 524288; dl = Wqkl + 524288; }
    else                  { src = Wv; dh = Wvh;           dl = Wvl; }
    const float4 v = ((const float4*)src)[i];
    const float vv[4] = {v.x, v.y, v.z, v.w};
    uint hp[4], lp[4];
#pragma unroll
    for (int j = 0; j < 4; ++j) {
        const ushort hb = f2bf(vv[j]);
        hp[j] = hb;
        lp[j] = f2bf(vv[j] - bf2f(hb));
    }
    uint2 H, L;
    H.x = hp[0] | (hp[1] << 16); H.y = hp[2] | (hp[3] << 16);
    L.x = lp[0] | (lp[1] << 16); L.y = lp[2] | (lp[3] << 16);
    ((uint2*)dh)[i] = H;
    ((uint2*)dl)[i] = L;
}

// ---------------------------------------------------------------------------
// MFMA 3-pass hi/lo bf16 GEMM body (NT, fp32-accurate): emits FP16 outputs.
// BM=128, BN=128, BK=64, 256 threads = 4 waves (2x2), 16x16x32 bf16.
// MODE 0: q/k fp16 write; MODE 1: vt fp16 write.
// ---------------------------------------------------------------------------
template<int BN, int KD, int MODE>
__device__ __forceinline__ void gemm3p_body(
    const ushort* __restrict__ Agh, const ushort* __restrict__ Agl,
    const ushort* __restrict__ Bgh, const ushort* __restrict__ Bgl,
    ushort* __restrict__ o0, ushort* __restrict__ o1, int Ntiles)
{
    constexpr int NF = BN / 32;
    __shared__ __align__(16) ushort Ah[128 * 64], Al[128 * 64];
    __shared__ __align__(16) ushort Bh[BN * 64],  Bl[BN * 64];

    const int cpx = gridDim.x >> 3;
    const int wg  = (blockIdx.x & 7) * cpx + (blockIdx.x >> 3);
    const int m0 = (wg / Ntiles) * 128;
    const int n0 = (wg % Ntiles) * BN;

    const int tid = threadIdx.x, w = tid >> 6, l = tid & 63;
    const int wr = w >> 1, wc = w & 1, g = l >> 4, c16 = l & 15;
    const int sr = l >> 3, sb = l & 7;

    f32x4 acc[4][NF];
#pragma unroll
    for (int mi = 0; mi < 4; ++mi)
#pragma unroll
        for (int ni = 0; ni < NF; ++ni) acc[mi][ni] = (f32x4){0.f, 0.f, 0.f, 0.f};

    for (int k0 = 0; k0 < KD; k0 += 64) {
        __syncthreads();
#pragma unroll
        for (int j = 0; j < 4; ++j) {
            const int rb = w * 32 + j * 8;
            const int r  = rb + sr;
            const size_t src = (size_t)(m0 + r) * KD + k0 + ((sb ^ (r & 7)) * 8);
            __builtin_amdgcn_global_load_lds(Agh + src, &Ah[rb * 64], 16, 0, 0);
            __builtin_amdgcn_global_load_lds(Agl + src, &Al[rb * 64], 16, 0, 0);
        }
#pragma unroll
        for (int j = 0; j < BN / 32; ++j) {
            const int rb = w * (BN / 4) + j * 8;
            const int r  = rb + sr;
            const size_t src = (size_t)(n0 + r) * KD + k0 + ((sb ^ (r & 7)) * 8);
            __builtin_amdgcn_global_load_lds(Bgh + src, &Bh[rb * 64], 16, 0, 0);
            __builtin_amdgcn_global_load_lds(Bgl + src, &Bl[rb * 64], 16, 0, 0);
        }
        asm volatile("s_waitcnt vmcnt(0)" ::: "memory");
        __syncthreads();

#pragma unroll
        for (int kh = 0; kh < 2; ++kh) {
            const int bsel = ((kh << 2) | g) ^ (c16 & 7);
            short8 afh[4], afl[4], bfh[NF], bfl[NF];
#pragma unroll
            for (int mi = 0; mi < 4; ++mi) {
                const int row = wr * 64 + mi * 16 + c16;
                afh[mi] = *(const short8*)&Ah[row * 64 + bsel * 8];
                afl[mi] = *(const short8*)&Al[row * 64 + bsel * 8];
            }
#pragma unroll
            for (int ni = 0; ni < NF; ++ni) {
                const int row = wc * (BN / 2) + ni * 16 + c16;
                bfh[ni] = *(const short8*)&Bh[row * 64 + bsel * 8];
                bfl[ni] = *(const short8*)&Bl[row * 64 + bsel * 8];
            }
#pragma unroll
            for (int mi = 0; mi < 4; ++mi)
#pragma unroll
                for (int ni = 0; ni < NF; ++ni) {
                    acc[mi][ni] = __builtin_amdgcn_mfma_f32_16x16x32_bf16(afh[mi], bfh[ni], acc[mi][ni], 0, 0, 0);
                    acc[mi][ni] = __builtin_amdgcn_mfma_f32_16x16x32_bf16(afl[mi], bfh[ni], acc[mi][ni], 0, 0, 0);
                    acc[mi][ni] = __builtin_amdgcn_mfma_f32_16x16x32_bf16(afh[mi], bfl[ni], acc[mi][ni], 0, 0, 0);
                }
        }
    }

#pragma unroll
    for (int mi = 0; mi < 4; ++mi)
#pragma unroll
        for (int ni = 0; ni < NF; ++ni) {
            const int n = n0 + wc * (BN / 2) + ni * 16 + c16;
            if constexpr (MODE == 0) {
                const int op = n >> 11, hh = (n >> 8) & 7, d = n & 255;
                ushort* tq = (op ? o1 : o0) + (size_t)hh * QE + d;
#pragma unroll
                for (int j = 0; j < 4; ++j) {
                    const int m = m0 + wr * 64 + mi * 16 + 4 * g + j;
                    tq[(size_t)m * 256] = f2h(acc[mi][ni][j]);
                }
            } else {
#pragma unroll
                for (int j = 0; j < 4; ++j) {
                    const int m = m0 + wr * 64 + mi * 16 + 4 * g + j;
                    o0[(size_t)m * NROWS + n] = f2h(acc[mi][ni][j]);
                }
            }
        }
}

__global__ __launch_bounds__(256) void gemm_qk(
    const ushort* __restrict__ Agh, const ushort* __restrict__ Agl,
    const ushort* __restrict__ Bgh, const ushort* __restrict__ Bgl,
    ushort* __restrict__ qf, ushort* __restrict__ kf)
{
    gemm3p_body<128, 256, 0>(Agh, Agl, Bgh, Bgl, qf, kf, 32);
}

__global__ __launch_bounds__(256) void gemm_vt(
    const ushort* __restrict__ Agh, const ushort* __restrict__ Agl,
    const ushort* __restrict__ Bgh, const ushort* __restrict__ Bgl,
    ushort* __restrict__ vt)
{
    gemm3p_body<128, 256, 1>(Agh, Agl, Bgh, Bgl, vt, nullptr, 64);
}

// ---------------------------------------------------------------------------
// K3: fp16 single-pass output projection: out[8192][256] = ocf x Wof^T + bo.
// ---------------------------------------------------------------------------
__global__ __launch_bounds__(256) void gemm_out_f16(
    const ushort* __restrict__ A, const ushort* __restrict__ Bw,
    const float* __restrict__ bias, float* __restrict__ fo)
{
    __shared__ __align__(16) ushort Ah[128 * 64];
    __shared__ __align__(16) ushort Bh[64 * 64];

    const int cpx = gridDim.x >> 3;
    const int wg  = (blockIdx.x & 7) * cpx + (blockIdx.x >> 3);
    const int m0 = (wg >> 2) * 128;
    const int n0 = (wg & 3) * 64;

    const int tid = threadIdx.x, w = tid >> 6, l = tid & 63;
    const int wr = w >> 1, wc = w & 1, g = l >> 4, c16 = l & 15;
    const int sr = l >> 3, sb = l & 7;

    f32x4 acc[4][2];
#pragma unroll
    for (int mi = 0; mi < 4; ++mi)
#pragma unroll
        for (int ni = 0; ni < 2; ++ni) acc[mi][ni] = (f32x4){0.f, 0.f, 0.f, 0.f};

    for (int k0 = 0; k0 < 2048; k0 += 64) {
        __syncthreads();
#pragma unroll
        for (int j = 0; j < 4; ++j) {
            const int rb = w * 32 + j * 8;
            const int r  = rb + sr;
            const size_t src = (size_t)(m0 + r) * 2048 + k0 + ((sb ^ (r & 7)) * 8);
            __builtin_amdgcn_global_load_lds(A + src, &Ah[rb * 64], 16, 0, 0);
        }
#pragma unroll
        for (int j = 0; j < 2; ++j) {
            const int rb = w * 16 + j * 8;
            const int r  = rb + sr;
            const size_t src = (size_t)(n0 + r) * 2048 + k0 + ((sb ^ (r & 7)) * 8);
            __builtin_amdgcn_global_load_lds(Bw + src, &Bh[rb * 64], 16, 0, 0);
        }
        asm volatile("s_waitcnt vmcnt(0)" ::: "memory");
        __syncthreads();

#pragma unroll
        for (int kh = 0; kh < 2; ++kh) {
            const int bsel = ((kh << 2) | g) ^ (c16 & 7);
            half8 af[4], bf[2];
#pragma unroll
            for (int mi = 0; mi < 4; ++mi)
                af[mi] = *(const half8*)&Ah[(wr * 64 + mi * 16 + c16) * 64 + bsel * 8];
#pragma unroll
            for (int ni = 0; ni < 2; ++ni)
                bf[ni] = *(const half8*)&Bh[(wc * 32 + ni * 16 + c16) * 64 + bsel * 8];
#pragma unroll
            for (int mi = 0; mi < 4; ++mi)
#pragma unroll
                for (int ni = 0; ni < 2; ++ni)
                    acc[mi][ni] = __builtin_amdgcn_mfma_f32_16x16x32_f16(af[mi], bf[ni], acc[mi][ni], 0, 0, 0);
        }
    }

#pragma unroll
    for (int mi = 0; mi < 4; ++mi)
#pragma unroll
        for (int ni = 0; ni < 2; ++ni) {
            const int n = n0 + wc * 32 + ni * 16 + c16;
            const float bb = bias[n];
#pragma unroll
            for (int j = 0; j < 4; ++j) {
                const int m = m0 + wr * 64 + mi * 16 + 4 * g + j;
                fo[(size_t)m * 256 + n] = acc[mi][ni][j] + bb;
            }
        }
}

// ---------------------------------------------------------------------------
// K2: fp16 MFMA flash attention — DIRECT-REGISTER fragments, no LDS staging,
// no barriers. 512 blocks = 64 hb x 8 qst (heavy-first, hb pinned per XCD),
// 4 independent waves x 32 q-rows. Each wave loops to its own causal bound
// nktw = 4*qst + w + 1 and reads K/V MFMA fragments straight from global
// (L1/L2-served). Softmax: per-lane deferred max (cross-lane shfl only in
// rare rescale branch), per-lane l partials reduced once in epilogue.
// LDS = 8KB P-bounce only.
// ---------------------------------------------------------------------------
__global__ __launch_bounds__(256, 2) void flash_mfma(
    const ushort* __restrict__ qf, const ushort* __restrict__ kf,
    const ushort* __restrict__ vt, ushort* __restrict__ ocf)
{
    __shared__ __align__(16) ushort Pls[4][2][512];

    const int bid = blockIdx.x;
    const int hb  = (bid & 7) * 8 + ((bid >> 3) & 7);  // same-XCD hb groups
    const int qst = 7 - (bid >> 6);                    // heavy-first
    const int h = hb >> 3, b = hb & 7;

    const int tid = threadIdx.x;
    const int w = tid >> 6, l = tid & 63;
    const int g = l >> 4, c16 = l & 15;
    const size_t qk_base = (size_t)h * QE + (size_t)b * (SEQ * EMBED);
    const size_t vt_base = (size_t)h * QE + (size_t)b * SEQ;

    const int psw = (c16 >> 1) & 3;
    const int qw0 = qst * 128 + w * 32;
    const int q0 = qw0 + c16;
    const int q1 = qw0 + 16 + c16;

    // Q fragments for both q-blocks
    half8 qfr0[8], qfr1[8];
    {
        const ushort* qr0 = qf + qk_base + (size_t)q0 * EMBED + g * 8;
        const ushort* qr1 = qf + qk_base + (size_t)q1 * EMBED + g * 8;
#pragma unroll
        for (int kc = 0; kc < 8; ++kc) {
            qfr0[kc] = *(const half8*)(qr0 + kc * 32);
            qfr1[kc] = *(const half8*)(qr1 + kc * 32);
        }
    }

    // per-lane fragment bases
    const ushort* kp0 = kf + qk_base + (size_t)c16 * EMBED + g * 8;   // K row c16
    const ushort* vp0 = vt + vt_base + (size_t)c16 * NROWS + g * 8;   // VT d-row c16

    f32x4 acc0[16], acc1[16];
#pragma unroll
    for (int dt = 0; dt < 16; ++dt) {
        acc0[dt] = (f32x4){0.f, 0.f, 0.f, 0.f};
        acc1[dt] = (f32x4){0.f, 0.f, 0.f, 0.f};
    }
    float m0r = -1e30f, m1r = -1e30f;
    float l0p = 0.f, l1p = 0.f;          // per-lane partials

    char* pw0 = (char*)&Pls[w][0][0];
    char* pw1 = (char*)&Pls[w][1][0];

    const int nktw = 4 * qst + w + 1;    // per-wave causal bound
    for (int kt = 0; kt < nktw; ++kt) {
        // ---- QK^T: direct global K fragments ----
        const ushort* kp = kp0 + (size_t)kt * (32 * EMBED);
        f32x4 s00 = (f32x4){0.f,0.f,0.f,0.f}, s01 = s00, s10 = s00, s11 = s00;
#pragma unroll
        for (int kc = 0; kc < 8; ++kc) {
            const half8 a0 = *(const half8*)(kp + kc * 32);
            const half8 a1 = *(const half8*)(kp + 16 * EMBED + kc * 32);
            s00 = __builtin_amdgcn_mfma_f32_16x16x32_f16(a0, qfr0[kc], s00, 0, 0, 0);
            s01 = __builtin_amdgcn_mfma_f32_16x16x32_f16(a0, qfr1[kc], s01, 0, 0, 0);
            s10 = __builtin_amdgcn_mfma_f32_16x16x32_f16(a1, qfr0[kc], s10, 0, 0, 0);
            s11 = __builtin_amdgcn_mfma_f32_16x16x32_f16(a1, qfr1[kc], s11, 0, 0, 0);
        }

        // ---- causal mask + per-lane max (no cross-lane in common path) ----
        const int k0b = kt * 32 + 4 * g;
        float p00[4], p10[4], p01[4], p11[4];
        float pm0 = -1e30f, pm1 = -1e30f;
#pragma unroll
        for (int r = 0; r < 4; ++r) {
            p00[r] = (k0b + r      > q0) ? -1e30f : s00[r];
            p10[r] = (k0b + 16 + r > q0) ? -1e30f : s10[r];
            p01[r] = (k0b + r      > q1) ? -1e30f : s01[r];
            p11[r] = (k0b + 16 + r > q1) ? -1e30f : s11[r];
            pm0 = fmaxf(pm0, fmaxf(p00[r], p10[r]));
            pm1 = fmaxf(pm1, fmaxf(p01[r], p11[r]));
        }

        // T13 defer-rescale: full reduce + rescale only when max grew past THR
        if (__any((pm0 > m0r + 8.f) || (pm1 > m1r + 8.f))) {
            float g0 = fmaxf(pm0, __shfl_xor(pm0, 16));
            g0 = fmaxf(g0, __shfl_xor(g0, 32));
            float g1 = fmaxf(pm1, __shfl_xor(pm1, 16));
            g1 = fmaxf(g1, __shfl_xor(g1, 32));
            const float m0n = fmaxf(m0r, g0);
            const float m1n = fmaxf(m1r, g1);
            const float sc0 = __expf(m0r - m0n);
            const float sc1 = __expf(m1r - m1n);
            l0p *= sc0; l1p *= sc1;
#pragma unroll
            for (int dt = 0; dt < 16; ++dt) { acc0[dt] *= sc0; acc1[dt] *= sc1; }
            m0r = m0n; m1r = m1n;
        }

        // ---- exp + per-lane l partials ----
#pragma unroll
        for (int r = 0; r < 4; ++r) {
            p00[r] = __expf(p00[r] - m0r);
            p10[r] = __expf(p10[r] - m0r);
            p01[r] = __expf(p01[r] - m1r);
            p11[r] = __expf(p11[r] - m1r);
            l0p += p00[r] + p10[r];
            l1p += p01[r] + p11[r];
        }

        // ---- P bounce: C-layout -> B-fragment via per-wave LDS (1KB each) ----
#pragma unroll
        for (int t = 0; t < 2; ++t)
#pragma unroll
            for (int u = 0; u < 2; ++u) {
                const int kk = 16 * t + 4 * g + 2 * u;
                const int off = c16 * 64 + (((kk >> 3) ^ psw) * 16) + (kk & 7) * 2;
                const float a0v = t ? p10[2 * u] : p00[2 * u];
                const float a1v = t ? p10[2 * u + 1] : p00[2 * u + 1];
                *(uint*)(pw0 + off) = (uint)f2h(a0v) | ((uint)f2h(a1v) << 16);
                const float b0v = t ? p11[2 * u] : p01[2 * u];
                const float b1v = t ? p11[2 * u + 1] : p01[2 * u + 1];
                *(uint*)(pw1 + off) = (uint)f2h(b0v) | ((uint)f2h(b1v) << 16);
            }
        const half8 pfrag0 = *(const half8*)(pw0 + c16 * 64 + ((g ^ psw) * 16));
        const half8 pfrag1 = *(const half8*)(pw1 + c16 * 64 + ((g ^ psw) * 16));

        // ---- PV: direct global VT fragments ----
        const ushort* vp = vp0 + kt * 32;
#pragma unroll
        for (int dt = 0; dt < 16; ++dt) {
            const half8 va = *(const half8*)(vp + (size_t)dt * (16 * NROWS));
            acc0[dt] = __builtin_amdgcn_mfma_f32_16x16x32_f16(va, pfrag0, acc0[dt], 0, 0, 0);
            acc1[dt] = __builtin_amdgcn_mfma_f32_16x16x32_f16(va, pfrag1, acc1[dt], 0, 0, 0);
        }
    }

    // ---- epilogue: reduce l partials across the 4 g-groups, write fp16 ----
    l0p += __shfl_xor(l0p, 16); l0p += __shfl_xor(l0p, 32);
    l1p += __shfl_xor(l1p, 16); l1p += __shfl_xor(l1p, 32);
    const float inv0 = 1.f / l0p;
    const float inv1 = 1.f / l1p;
    ushort* orow0 = ocf + ((size_t)(b * SEQ) + q0) * (HEADS * EMBED) + h * EMBED;
    ushort* orow1 = ocf + ((size_t)(b * SEQ) + q1) * (HEADS * EMBED) + h * EMBED;
#pragma unroll
    for (int dt = 0; dt < 16; ++dt) {
        const f32x4 o0 = acc0[dt] * inv0;
        const f32x4 o1 = acc1[dt] * inv1;
        uint2 P2;
        P2.x = (uint)f2h(o0[0]) | ((uint)f2h(o0[1]) << 16);
        P2.y = (uint)f2h(o0[2]) | ((uint)f2h(o0[3]) << 16);
        *(uint2*)(orow0 + dt * 16 + 4 * g) = P2;
        P2.x = (uint)f2h(o1[0]) | ((uint)f2h(o1[1]) << 16);
        P2.y = (uint)f2h(o1[2]) | ((uint)f2h(o1[3]) << 16);
        *(uint2*)(orow1 + dt * 16 + 4 * g) = P2;
    }
}

extern "C" void kernel_launch(void* const* d_in, const int* in_sizes, int n_in,
                              void* d_out, int out_size, void* d_ws, size_t ws_size,
                              hipStream_t stream) {
    const float* X  = (const float*)d_in[0];
    const float* Wq = (const float*)d_in[1];
    const float* Wk = (const float*)d_in[2];
    const float* Wv = (const float*)d_in[3];
    const float* Wo = (const float*)d_in[4];
    const float* bo = (const float*)d_in[5];

    ushort* ws16 = (ushort*)d_ws;
    ushort* qf   = ws16;                     // [8][8192][256] fp16
    ushort* kf   = ws16 +  8 * QE;           // fp16
    ushort* vtb  = ws16 + 16 * QE;           // [8][256][8192] fp16
    ushort* ocf  = ws16 + 24 * QE;           // [8192][2048] fp16
    ushort* ex   = ws16 + 32 * QE;
    ushort* Xh   = ex;
    ushort* Xl   = ex + 2097152;
    ushort* Wqkh = ex + 2 * 2097152;
    ushort* Wqkl = ex + 3 * 2097152;
    ushort* Wvh  = ex + 4 * 2097152;
    ushort* Wvl  = ex + 4 * 2097152 + 524288;
    ushort* Wof  = ex + 5 * 2097152;
    float*  out  = (float*)d_out;

    split_bf16<<<2048, 256, 0, stream>>>(X, Xh, Xl, 524288);
    split_weights<<<2048, 256, 0, stream>>>(Wq, Wk, Wv, Wo,
                                            Wqkh, Wqkl, Wvh, Wvl, Wof);

    gemm_qk<<<2048, 256, 0, stream>>>(Xh, Xl, Wqkh, Wqkl, qf, kf);
    gemm_vt<<<1024, 256, 0, stream>>>(Wvh, Wvl, Xh, Xl, vtb);

    flash_mfma<<<512, 256, 0, stream>>>(qf, kf, vtb, ocf);

    gemm_out_f16<<<256, 256, 0, stream>>>(ocf, Wof, bo, out);
}

// Round 10
// 177.233 us; speedup vs baseline: 1.6250x; 1.6250x over previous
//
#include <hip/hip_runtime.h>
#include <hip/hip_bf16.h>

#define EMBED 256
#define HEADS 8
#define BATCH 8
#define SEQ   1024
#define NROWS 8192

typedef __attribute__((ext_vector_type(8))) short short8;     // 8 bf16
typedef __attribute__((ext_vector_type(8))) _Float16 half8;   // 8 fp16
typedef __attribute__((ext_vector_type(4))) float f32x4;
typedef unsigned int  uint;
typedef unsigned short ushort;

#define QE   ((size_t)2097152)   /* per-head elems: 8192*256 */

__device__ __forceinline__ ushort f2bf(float f) {
    union { __hip_bfloat16 b; ushort u; } cv; cv.b = __float2bfloat16(f); return cv.u;
}
__device__ __forceinline__ float bf2f(ushort s) {
    union { ushort u; __hip_bfloat16 b; } cv; cv.u = s; return __bfloat162float(cv.b);
}
__device__ __forceinline__ ushort f2h(float f) {
    union { _Float16 h; ushort u; } cv; cv.h = (_Float16)f; return cv.u;
}

// ---------------------------------------------------------------------------
// K0a: X hi/lo bf16 split (float4-vectorized). n4 = elems/4.
// ---------------------------------------------------------------------------
__global__ __launch_bounds__(256) void split_bf16(
    const float* __restrict__ src, ushort* __restrict__ dh,
    ushort* __restrict__ dl, int n4)
{
    const int i = blockIdx.x * 256 + threadIdx.x;
    if (i >= n4) return;
    const float4 v = ((const float4*)src)[i];
    const float vv[4] = {v.x, v.y, v.z, v.w};
    uint hp[4], lp[4];
#pragma unroll
    for (int j = 0; j < 4; ++j) {
        const ushort hb = f2bf(vv[j]);
        hp[j] = hb;
        lp[j] = f2bf(vv[j] - bf2f(hb));
    }
    uint2 H, L;
    H.x = hp[0] | (hp[1] << 16); H.y = hp[2] | (hp[3] << 16);
    L.x = lp[0] | (lp[1] << 16); L.y = lp[2] | (lp[3] << 16);
    ((uint2*)dh)[i] = H;
    ((uint2*)dl)[i] = L;
}

// K0b: weight prep. Regions 0..2 (Wq,Wk,Wv): bf16 hi/lo split.
// Region 3 (Wo): fp16 single.
__global__ __launch_bounds__(256) void split_weights(
    const float* __restrict__ Wq, const float* __restrict__ Wk,
    const float* __restrict__ Wv, const float* __restrict__ Wo,
    ushort* __restrict__ Wqkh, ushort* __restrict__ Wqkl,
    ushort* __restrict__ Wvh,  ushort* __restrict__ Wvl,
    ushort* __restrict__ Wof)
{
    const int blk = blockIdx.x;
    const int region = blk >> 9;            // 0..3
    const int i = (blk & 511) * 256 + threadIdx.x;   // < 131072 float4s
    if (region == 3) {
        const float4 v = ((const float4*)Wo)[i];
        uint2 P;
        P.x = (uint)f2h(v.x) | ((uint)f2h(v.y) << 16);
        P.y = (uint)f2h(v.z) | ((uint)f2h(v.w) << 16);
        ((uint2*)Wof)[i] = P;
        return;
    }
    const float* src; ushort *dh, *dl;
    if (region == 0)      { src = Wq; dh = Wqkh;          dl = Wqkl; }
    else if (region == 1) { src = Wk; dh = Wqkh + 524288; dl = Wqkl + 524288; }
    else                  { src = Wv; dh = Wvh;           dl = Wvl; }
    const float4 v = ((const float4*)src)[i];
    const float vv[4] = {v.x, v.y, v.z, v.w};
    uint hp[4], lp[4];
#pragma unroll
    for (int j = 0; j < 4; ++j) {
        const ushort hb = f2bf(vv[j]);
        hp[j] = hb;
        lp[j] = f2bf(vv[j] - bf2f(hb));
    }
    uint2 H, L;
    H.x = hp[0] | (hp[1] << 16); H.y = hp[2] | (hp[3] << 16);
    L.x = lp[0] | (lp[1] << 16); L.y = lp[2] | (lp[3] << 16);
    ((uint2*)dh)[i] = H;
    ((uint2*)dl)[i] = L;
}

// ---------------------------------------------------------------------------
// MFMA 3-pass hi/lo bf16 GEMM core (NT): BM=BN=128, BK=64, KD=256,
// 256 threads = 4 waves (2x2). LDS passed in (shared across call sites).
// mode 0: q/k fp16 write; mode 1: vt fp16 write.
// ---------------------------------------------------------------------------
__device__ __forceinline__ void gemm3p_core(
    const ushort* __restrict__ Agh, const ushort* __restrict__ Agl,
    const ushort* __restrict__ Bgh, const ushort* __restrict__ Bgl,
    ushort* __restrict__ o0, ushort* __restrict__ o1,
    ushort* Ah, ushort* Al, ushort* Bh, ushort* Bl,
    int wg, int Ntiles, int mode)
{
    const int m0 = (wg / Ntiles) * 128;
    const int n0 = (wg % Ntiles) * 128;

    const int tid = threadIdx.x, w = tid >> 6, l = tid & 63;
    const int wr = w >> 1, wc = w & 1, g = l >> 4, c16 = l & 15;
    const int sr = l >> 3, sb = l & 7;

    f32x4 acc[4][4];
#pragma unroll
    for (int mi = 0; mi < 4; ++mi)
#pragma unroll
        for (int ni = 0; ni < 4; ++ni) acc[mi][ni] = (f32x4){0.f, 0.f, 0.f, 0.f};

    for (int k0 = 0; k0 < 256; k0 += 64) {
        __syncthreads();
#pragma unroll
        for (int j = 0; j < 4; ++j) {
            const int rb = w * 32 + j * 8;
            const int r  = rb + sr;
            const size_t src = (size_t)(m0 + r) * 256 + k0 + ((sb ^ (r & 7)) * 8);
            __builtin_amdgcn_global_load_lds(Agh + src, &Ah[rb * 64], 16, 0, 0);
            __builtin_amdgcn_global_load_lds(Agl + src, &Al[rb * 64], 16, 0, 0);
        }
#pragma unroll
        for (int j = 0; j < 4; ++j) {
            const int rb = w * 32 + j * 8;
            const int r  = rb + sr;
            const size_t src = (size_t)(n0 + r) * 256 + k0 + ((sb ^ (r & 7)) * 8);
            __builtin_amdgcn_global_load_lds(Bgh + src, &Bh[rb * 64], 16, 0, 0);
            __builtin_amdgcn_global_load_lds(Bgl + src, &Bl[rb * 64], 16, 0, 0);
        }
        asm volatile("s_waitcnt vmcnt(0)" ::: "memory");
        __syncthreads();

#pragma unroll
        for (int kh = 0; kh < 2; ++kh) {
            const int bsel = ((kh << 2) | g) ^ (c16 & 7);
            short8 afh[4], afl[4], bfh[4], bfl[4];
#pragma unroll
            for (int mi = 0; mi < 4; ++mi) {
                const int row = wr * 64 + mi * 16 + c16;
                afh[mi] = *(const short8*)&Ah[row * 64 + bsel * 8];
                afl[mi] = *(const short8*)&Al[row * 64 + bsel * 8];
            }
#pragma unroll
            for (int ni = 0; ni < 4; ++ni) {
                const int row = wc * 64 + ni * 16 + c16;
                bfh[ni] = *(const short8*)&Bh[row * 64 + bsel * 8];
                bfl[ni] = *(const short8*)&Bl[row * 64 + bsel * 8];
            }
#pragma unroll
            for (int mi = 0; mi < 4; ++mi)
#pragma unroll
                for (int ni = 0; ni < 4; ++ni) {
                    acc[mi][ni] = __builtin_amdgcn_mfma_f32_16x16x32_bf16(afh[mi], bfh[ni], acc[mi][ni], 0, 0, 0);
                    acc[mi][ni] = __builtin_amdgcn_mfma_f32_16x16x32_bf16(afl[mi], bfh[ni], acc[mi][ni], 0, 0, 0);
                    acc[mi][ni] = __builtin_amdgcn_mfma_f32_16x16x32_bf16(afh[mi], bfl[ni], acc[mi][ni], 0, 0, 0);
                }
        }
    }

#pragma unroll
    for (int mi = 0; mi < 4; ++mi)
#pragma unroll
        for (int ni = 0; ni < 4; ++ni) {
            const int n = n0 + wc * 64 + ni * 16 + c16;
            if (mode == 0) {
                const int op = n >> 11, hh = (n >> 8) & 7, d = n & 255;
                ushort* tq = (op ? o1 : o0) + (size_t)hh * QE + d;
#pragma unroll
                for (int j = 0; j < 4; ++j) {
                    const int m = m0 + wr * 64 + mi * 16 + 4 * g + j;
                    tq[(size_t)m * 256] = f2h(acc[mi][ni][j]);
                }
            } else {
#pragma unroll
                for (int j = 0; j < 4; ++j) {
                    const int m = m0 + wr * 64 + mi * 16 + 4 * g + j;
                    o0[(size_t)m * NROWS + n] = f2h(acc[mi][ni][j]);
                }
            }
        }
}

// Merged QK + VT projection launch: bid<2048 -> qk GEMM, else vt GEMM.
__global__ __launch_bounds__(256) void gemm_qkvt(
    const ushort* __restrict__ Xh, const ushort* __restrict__ Xl,
    const ushort* __restrict__ Wqkh, const ushort* __restrict__ Wqkl,
    const ushort* __restrict__ Wvh, const ushort* __restrict__ Wvl,
    ushort* __restrict__ qf, ushort* __restrict__ kf, ushort* __restrict__ vtb)
{
    __shared__ __align__(16) ushort Ah[128 * 64], Al[128 * 64];
    __shared__ __align__(16) ushort Bh[128 * 64], Bl[128 * 64];
    const int bid = blockIdx.x;
    if (bid < 2048) {
        const int wg = (bid & 7) * 256 + (bid >> 3);
        gemm3p_core(Xh, Xl, Wqkh, Wqkl, qf, kf, Ah, Al, Bh, Bl, wg, 32, 0);
    } else {
        const int b2 = bid - 2048;
        const int wg = (b2 & 7) * 128 + (b2 >> 3);
        gemm3p_core(Wvh, Wvl, Xh, Xl, vtb, nullptr, Ah, Al, Bh, Bl, wg, 64, 1);
    }
}

// ---------------------------------------------------------------------------
// K3: fp16 single-pass output projection: out[8192][256] = ocf x Wof^T + bo.
// ---------------------------------------------------------------------------
__global__ __launch_bounds__(256) void gemm_out_f16(
    const ushort* __restrict__ A, const ushort* __restrict__ Bw,
    const float* __restrict__ bias, float* __restrict__ fo)
{
    __shared__ __align__(16) ushort Ah[128 * 64];
    __shared__ __align__(16) ushort Bh[64 * 64];

    const int cpx = gridDim.x >> 3;
    const int wg  = (blockIdx.x & 7) * cpx + (blockIdx.x >> 3);
    const int m0 = (wg >> 2) * 128;
    const int n0 = (wg & 3) * 64;

    const int tid = threadIdx.x, w = tid >> 6, l = tid & 63;
    const int wr = w >> 1, wc = w & 1, g = l >> 4, c16 = l & 15;
    const int sr = l >> 3, sb = l & 7;

    f32x4 acc[4][2];
#pragma unroll
    for (int mi = 0; mi < 4; ++mi)
#pragma unroll
        for (int ni = 0; ni < 2; ++ni) acc[mi][ni] = (f32x4){0.f, 0.f, 0.f, 0.f};

    for (int k0 = 0; k0 < 2048; k0 += 64) {
        __syncthreads();
#pragma unroll
        for (int j = 0; j < 4; ++j) {
            const int rb = w * 32 + j * 8;
            const int r  = rb + sr;
            const size_t src = (size_t)(m0 + r) * 2048 + k0 + ((sb ^ (r & 7)) * 8);
            __builtin_amdgcn_global_load_lds(A + src, &Ah[rb * 64], 16, 0, 0);
        }
#pragma unroll
        for (int j = 0; j < 2; ++j) {
            const int rb = w * 16 + j * 8;
            const int r  = rb + sr;
            const size_t src = (size_t)(n0 + r) * 2048 + k0 + ((sb ^ (r & 7)) * 8);
            __builtin_amdgcn_global_load_lds(Bw + src, &Bh[rb * 64], 16, 0, 0);
        }
        asm volatile("s_waitcnt vmcnt(0)" ::: "memory");
        __syncthreads();

#pragma unroll
        for (int kh = 0; kh < 2; ++kh) {
            const int bsel = ((kh << 2) | g) ^ (c16 & 7);
            half8 af[4], bf[2];
#pragma unroll
            for (int mi = 0; mi < 4; ++mi)
                af[mi] = *(const half8*)&Ah[(wr * 64 + mi * 16 + c16) * 64 + bsel * 8];
#pragma unroll
            for (int ni = 0; ni < 2; ++ni)
                bf[ni] = *(const half8*)&Bh[(wc * 32 + ni * 16 + c16) * 64 + bsel * 8];
#pragma unroll
            for (int mi = 0; mi < 4; ++mi)
#pragma unroll
                for (int ni = 0; ni < 2; ++ni)
                    acc[mi][ni] = __builtin_amdgcn_mfma_f32_16x16x32_f16(af[mi], bf[ni], acc[mi][ni], 0, 0, 0);
        }
    }

#pragma unroll
    for (int mi = 0; mi < 4; ++mi)
#pragma unroll
        for (int ni = 0; ni < 2; ++ni) {
            const int n = n0 + wc * 32 + ni * 16 + c16;
            const float bb = bias[n];
#pragma unroll
            for (int j = 0; j < 4; ++j) {
                const int m = m0 + wr * 64 + mi * 16 + 4 * g + j;
                fo[(size_t)m * 256 + n] = acc[mi][ni][j] + bb;
            }
        }
}

// ---------------------------------------------------------------------------
// K2: fp16 MFMA flash attention — occupancy build.
// 16 q-rows/wave (acc=64 AGPR), __launch_bounds__(256,3) -> target 3 waves/SIMD,
// LDS 52KB (K dbuf 32K + VT single 16K + P 4K) -> 3 blocks/CU = 12 waves/CU.
// 1024 blocks = 64 hb x 16 qst, heavy-first, hb pinned per XCD.
// Iter: issue VT[kt]+K[kt+1] -> QK+softmax (hides loads) -> vmcnt0+barrier ->
// PV -> barrier (frees VT buffer). Per-lane deferred softmax + defer-rescale.
// ---------------------------------------------------------------------------
__global__ __launch_bounds__(256, 3) void flash_mfma(
    const ushort* __restrict__ qf, const ushort* __restrict__ kf,
    const ushort* __restrict__ vt, ushort* __restrict__ ocf)
{
    __shared__ __align__(16) ushort Ks[2][32 * 256];
    __shared__ __align__(16) ushort VTs[256 * 32];
    __shared__ __align__(16) ushort Pls[4][512];

    const int bid = blockIdx.x;
    const int idx = bid >> 3;
    const int hb  = (bid & 7) * 8 + (idx & 7);   // same-XCD hb groups
    const int qst = 15 - (idx >> 3);             // heavy-first
    const int h = hb >> 3, b = hb & 7;

    const int tid = threadIdx.x;
    const int w = tid >> 6, l = tid & 63;
    const int g = l >> 4, c16 = l & 15;
    const size_t qk_base = (size_t)h * QE + (size_t)b * (SEQ * EMBED);
    const size_t vt_base = (size_t)h * QE + (size_t)b * SEQ;

    const int psw = (c16 >> 1) & 3;
    const int rsw = c16 & 7;
    const int qw0 = qst * 64 + w * 16;
    const int q0 = qw0 + c16;

    // Q fragments (stationary)
    half8 qfr[8];
    {
        const ushort* qr = qf + qk_base + (size_t)q0 * EMBED + g * 8;
#pragma unroll
        for (int kc = 0; kc < 8; ++kc)
            qfr[kc] = *(const half8*)(qr + kc * 32);
    }

    // staging: uniform bases + 32-bit lane offsets
    const ushort* kbase = kf + qk_base;
    const ushort* vbase = vt + vt_base;
    const int krow_l = l >> 5, kblk = l & 31;
    const int vd_l = l >> 2,  vblk = l & 3;
    uint koff[4], voff[4];
#pragma unroll
    for (int j = 0; j < 4; ++j) {
        const int row = 8 * w + 2 * j + krow_l;
        koff[j] = (uint)(row * EMBED + ((kblk ^ (row & 7)) * 8));
        const int d = w * 64 + j * 16 + vd_l;
        const int phi = ((d >> 1) ^ (d >> 3)) & 3;
        voff[j] = (uint)(d * NROWS + ((vblk ^ phi) * 8));
    }

    f32x4 acc[16];
#pragma unroll
    for (int dt = 0; dt < 16; ++dt) acc[dt] = (f32x4){0.f, 0.f, 0.f, 0.f};
    float m_r = -1e30f, l_p = 0.f;   // per-lane deferred max + l partial

    char* pw = (char*)&Pls[w][0];
    const int nkt = 2 * qst + 2;

    // prologue: stage K[0]
#pragma unroll
    for (int j = 0; j < 4; ++j)
        __builtin_amdgcn_global_load_lds(kbase + koff[j], &Ks[0][(8 * w + 2 * j) * 256], 16, 0, 0);
    asm volatile("s_waitcnt vmcnt(0)" ::: "memory");
    __syncthreads();

    for (int kt = 0; kt < nkt; ++kt) {
        // issue VT[kt] (single buffer; prior PV reads done at last barrier)
#pragma unroll
        for (int j = 0; j < 4; ++j)
            __builtin_amdgcn_global_load_lds(vbase + voff[j] + kt * 32,
                                             &VTs[(w * 64 + j * 16) * 32], 16, 0, 0);
        // issue K[kt+1] into alternate buffer
        if (kt + 1 < nkt) {
            const ushort* kb = kbase + (size_t)(kt + 1) * (32 * EMBED);
#pragma unroll
            for (int j = 0; j < 4; ++j)
                __builtin_amdgcn_global_load_lds(kb + koff[j],
                                                 &Ks[(kt + 1) & 1][(8 * w + 2 * j) * 256], 16, 0, 0);
        }

        const bool active = (kt * 32 <= qw0 + 15);
        if (active) {
            // ---- QK^T on staged K[kt] ----
            const ushort* Kb = &Ks[kt & 1][0];
            f32x4 s0 = (f32x4){0.f, 0.f, 0.f, 0.f};
            f32x4 s1 = (f32x4){0.f, 0.f, 0.f, 0.f};
#pragma unroll
            for (int kc = 0; kc < 8; ++kc) {
                const int blk = ((kc * 4 + g) ^ rsw) * 8;
                const half8 a0 = *(const half8*)&Kb[c16 * 256 + blk];
                const half8 a1 = *(const half8*)&Kb[(c16 + 16) * 256 + blk];
                s0 = __builtin_amdgcn_mfma_f32_16x16x32_f16(a0, qfr[kc], s0, 0, 0, 0);
                s1 = __builtin_amdgcn_mfma_f32_16x16x32_f16(a1, qfr[kc], s1, 0, 0, 0);
            }
            // ---- mask + per-lane deferred softmax ----
            const int k0b = kt * 32 + 4 * g;
            float p0[4], p1[4];
            float pm = -1e30f;
#pragma unroll
            for (int r = 0; r < 4; ++r) {
                p0[r] = (k0b + r      > q0) ? -1e30f : s0[r];
                p1[r] = (k0b + 16 + r > q0) ? -1e30f : s1[r];
                pm = fmaxf(pm, fmaxf(p0[r], p1[r]));
            }
            if (__any(pm > m_r + 8.f)) {
                float gm = fmaxf(pm, __shfl_xor(pm, 16));
                gm = fmaxf(gm, __shfl_xor(gm, 32));
                const float mn = fmaxf(m_r, gm);
                const float sc = __expf(m_r - mn);
                l_p *= sc;
#pragma unroll
                for (int dt = 0; dt < 16; ++dt) acc[dt] *= sc;
                m_r = mn;
            }
#pragma unroll
            for (int r = 0; r < 4; ++r) {
                p0[r] = __expf(p0[r] - m_r);
                p1[r] = __expf(p1[r] - m_r);
                l_p += p0[r] + p1[r];
            }
            // ---- P bounce write (read after barrier) ----
#pragma unroll
            for (int t = 0; t < 2; ++t)
#pragma unroll
                for (int u = 0; u < 2; ++u) {
                    const int kk = 16 * t + 4 * g + 2 * u;
                    const int off = c16 * 64 + (((kk >> 3) ^ psw) * 16) + (kk & 7) * 2;
                    const float lo = t ? p1[2 * u] : p0[2 * u];
                    const float hi = t ? p1[2 * u + 1] : p0[2 * u + 1];
                    *(uint*)(pw + off) = (uint)f2h(lo) | ((uint)f2h(hi) << 16);
                }
        }

        asm volatile("s_waitcnt vmcnt(0)" ::: "memory");
        __syncthreads();   // VT[kt] + K[kt+1] landed & visible to all waves

        if (active) {
            const half8 pfrag = *(const half8*)(pw + c16 * 64 + ((g ^ psw) * 16));
#pragma unroll
            for (int dt = 0; dt < 16; ++dt) {
                const int d = dt * 16 + c16;
                const int phi = ((d >> 1) ^ (d >> 3)) & 3;
                const half8 va = *(const half8*)&VTs[d * 32 + ((g ^ phi) * 8)];
                acc[dt] = __builtin_amdgcn_mfma_f32_16x16x32_f16(va, pfrag, acc[dt], 0, 0, 0);
            }
        }
        __syncthreads();   // PV reads done -> VT buffer free for next iter
    }

    // ---- epilogue ----
    l_p += __shfl_xor(l_p, 16);
    l_p += __shfl_xor(l_p, 32);
    const float inv = 1.f / l_p;
    ushort* orow = ocf + ((size_t)(b * SEQ) + q0) * (HEADS * EMBED) + h * EMBED;
#pragma unroll
    for (int dt = 0; dt < 16; ++dt) {
        const f32x4 o = acc[dt] * inv;
        uint2 P2;
        P2.x = (uint)f2h(o[0]) | ((uint)f2h(o[1]) << 16);
        P2.y = (uint)f2h(o[2]) | ((uint)f2h(o[3]) << 16);
        *(uint2*)(orow + dt * 16 + 4 * g) = P2;
    }
}

extern "C" void kernel_launch(void* const* d_in, const int* in_sizes, int n_in,
                              void* d_out, int out_size, void* d_ws, size_t ws_size,
                              hipStream_t stream) {
    const float* X  = (const float*)d_in[0];
    const float* Wq = (const float*)d_in[1];
    const float* Wk = (const float*)d_in[2];
    const float* Wv = (const float*)d_in[3];
    const float* Wo = (const float*)d_in[4];
    const float* bo = (const float*)d_in[5];

    ushort* ws16 = (ushort*)d_ws;
    ushort* qf   = ws16;                     // [8][8192][256] fp16
    ushort* kf   = ws16 +  8 * QE;           // fp16
    ushort* vtb  = ws16 + 16 * QE;           // [8][256][8192] fp16
    ushort* ocf  = ws16 + 24 * QE;           // [8192][2048] fp16
    ushort* ex   = ws16 + 32 * QE;
    ushort* Xh   = ex;
    ushort* Xl   = ex + 2097152;
    ushort* Wqkh = ex + 2 * 2097152;
    ushort* Wqkl = ex + 3 * 2097152;
    ushort* Wvh  = ex + 4 * 2097152;
    ushort* Wvl  = ex + 4 * 2097152 + 524288;
    ushort* Wof  = ex + 5 * 2097152;
    float*  out  = (float*)d_out;

    split_bf16<<<2048, 256, 0, stream>>>(X, Xh, Xl, 524288);
    split_weights<<<2048, 256, 0, stream>>>(Wq, Wk, Wv, Wo,
                                            Wqkh, Wqkl, Wvh, Wvl, Wof);

    // merged QK + VT projection (qk: 2048 blocks, vt: 1024 blocks)
    gemm_qkvt<<<3072, 256, 0, stream>>>(Xh, Xl, Wqkh, Wqkl, Wvh, Wvl, qf, kf, vtb);

    flash_mfma<<<1024, 256, 0, stream>>>(qf, kf, vtb, ocf);

    gemm_out_f16<<<256, 256, 0, stream>>>(ocf, Wof, bo, out);
}

// Round 11
// 141.411 us; speedup vs baseline: 2.0366x; 1.2533x over previous
//
#include <hip/hip_runtime.h>
#include <hip/hip_bf16.h>

#define EMBED 256
#define HEADS 8
#define BATCH 8
#define SEQ   1024
#define NROWS 8192

typedef __attribute__((ext_vector_type(8))) _Float16 half8;   // 8 fp16
typedef __attribute__((ext_vector_type(4))) float f32x4;
typedef unsigned int  uint;
typedef unsigned short ushort;

#define QE   ((size_t)2097152)   /* per-head elems: 8192*256 */

__device__ __forceinline__ ushort f2h(float f) {
    union { _Float16 h; ushort u; } cv; cv.h = (_Float16)f; return cv.u;
}

// ---------------------------------------------------------------------------
// K0: fp32 -> fp16 convert for X and all weights, one launch.
// Regions (by float4 index): X 524288, Wq 131072, Wk 131072, Wv 131072,
// Wo 131072 -> 4096 blocks x 256 threads, 1 float4 each.
// ---------------------------------------------------------------------------
__global__ __launch_bounds__(256) void convert_f16(
    const float* __restrict__ X,  const float* __restrict__ Wq,
    const float* __restrict__ Wk, const float* __restrict__ Wv,
    const float* __restrict__ Wo,
    ushort* __restrict__ Xf, ushort* __restrict__ Wqkf,
    ushort* __restrict__ Wvf, ushort* __restrict__ Wof)
{
    const int blk = blockIdx.x;
    const float* src; ushort* dst; int i;
    if (blk < 2048)      { src = X;  dst = Xf;            i = blk * 256 + threadIdx.x; }
    else if (blk < 2560) { src = Wq; dst = Wqkf;          i = (blk - 2048) * 256 + threadIdx.x; }
    else if (blk < 3072) { src = Wk; dst = Wqkf + 524288; i = (blk - 2560) * 256 + threadIdx.x; }
    else if (blk < 3584) { src = Wv; dst = Wvf;           i = (blk - 3072) * 256 + threadIdx.x; }
    else                 { src = Wo; dst = Wof;           i = (blk - 3584) * 256 + threadIdx.x; }
    const float4 v = ((const float4*)src)[i];
    uint2 P;
    P.x = (uint)f2h(v.x) | ((uint)f2h(v.y) << 16);
    P.y = (uint)f2h(v.z) | ((uint)f2h(v.w) << 16);
    ((uint2*)dst)[i] = P;
}

// ---------------------------------------------------------------------------
// Single-pass fp16 MFMA GEMM core (NT): BM=BN=128, BK=64, KD=256,
// 256 threads = 4 waves (2x2). Staging via global_load_lds w=16 with
// source pre-swizzle ^(row&7) on 16B blocks; LDS 32KB.
// mode 0: q/k fp16 write (n -> [q|k][head][d]); mode 1: vt fp16 write.
// ---------------------------------------------------------------------------
__device__ __forceinline__ void gemm1p_core(
    const ushort* __restrict__ Ag, const ushort* __restrict__ Bg,
    ushort* __restrict__ o0, ushort* __restrict__ o1,
    ushort* Ah, ushort* Bh, int wg, int Ntiles, int mode)
{
    const int m0 = (wg / Ntiles) * 128;
    const int n0 = (wg % Ntiles) * 128;

    const int tid = threadIdx.x, w = tid >> 6, l = tid & 63;
    const int wr = w >> 1, wc = w & 1, g = l >> 4, c16 = l & 15;
    const int sr = l >> 3, sb = l & 7;

    f32x4 acc[4][4];
#pragma unroll
    for (int mi = 0; mi < 4; ++mi)
#pragma unroll
        for (int ni = 0; ni < 4; ++ni) acc[mi][ni] = (f32x4){0.f, 0.f, 0.f, 0.f};

    for (int k0 = 0; k0 < 256; k0 += 64) {
        __syncthreads();
#pragma unroll
        for (int j = 0; j < 4; ++j) {
            const int rb = w * 32 + j * 8;
            const int r  = rb + sr;
            const size_t srcA = (size_t)(m0 + r) * 256 + k0 + ((sb ^ (r & 7)) * 8);
            __builtin_amdgcn_global_load_lds(Ag + srcA, &Ah[rb * 64], 16, 0, 0);
            const size_t srcB = (size_t)(n0 + r) * 256 + k0 + ((sb ^ (r & 7)) * 8);
            __builtin_amdgcn_global_load_lds(Bg + srcB, &Bh[rb * 64], 16, 0, 0);
        }
        asm volatile("s_waitcnt vmcnt(0)" ::: "memory");
        __syncthreads();

#pragma unroll
        for (int kh = 0; kh < 2; ++kh) {
            const int bsel = ((kh << 2) | g) ^ (c16 & 7);
            half8 af[4], bf[4];
#pragma unroll
            for (int mi = 0; mi < 4; ++mi)
                af[mi] = *(const half8*)&Ah[(wr * 64 + mi * 16 + c16) * 64 + bsel * 8];
#pragma unroll
            for (int ni = 0; ni < 4; ++ni)
                bf[ni] = *(const half8*)&Bh[(wc * 64 + ni * 16 + c16) * 64 + bsel * 8];
#pragma unroll
            for (int mi = 0; mi < 4; ++mi)
#pragma unroll
                for (int ni = 0; ni < 4; ++ni)
                    acc[mi][ni] = __builtin_amdgcn_mfma_f32_16x16x32_f16(af[mi], bf[ni], acc[mi][ni], 0, 0, 0);
        }
    }

#pragma unroll
    for (int mi = 0; mi < 4; ++mi)
#pragma unroll
        for (int ni = 0; ni < 4; ++ni) {
            const int n = n0 + wc * 64 + ni * 16 + c16;
            if (mode == 0) {
                const int op = n >> 11, hh = (n >> 8) & 7, d = n & 255;
                ushort* tq = (op ? o1 : o0) + (size_t)hh * QE + d;
#pragma unroll
                for (int j = 0; j < 4; ++j) {
                    const int m = m0 + wr * 64 + mi * 16 + 4 * g + j;
                    tq[(size_t)m * 256] = f2h(acc[mi][ni][j]);
                }
            } else {
#pragma unroll
                for (int j = 0; j < 4; ++j) {
                    const int m = m0 + wr * 64 + mi * 16 + 4 * g + j;
                    o0[(size_t)m * NROWS + n] = f2h(acc[mi][ni][j]);
                }
            }
        }
}

// Merged QK + VT projection launch: bid<2048 -> qk GEMM, else vt GEMM.
__global__ __launch_bounds__(256) void gemm_qkvt(
    const ushort* __restrict__ Xf,
    const ushort* __restrict__ Wqkf, const ushort* __restrict__ Wvf,
    ushort* __restrict__ qf, ushort* __restrict__ kf, ushort* __restrict__ vtb)
{
    __shared__ __align__(16) ushort Ah[128 * 64];
    __shared__ __align__(16) ushort Bh[128 * 64];
    const int bid = blockIdx.x;
    if (bid < 2048) {
        const int wg = (bid & 7) * 256 + (bid >> 3);
        gemm1p_core(Xf, Wqkf, qf, kf, Ah, Bh, wg, 32, 0);
    } else {
        const int b2 = bid - 2048;
        const int wg = (b2 & 7) * 128 + (b2 >> 3);
        gemm1p_core(Wvf, Xf, vtb, nullptr, Ah, Bh, wg, 64, 1);
    }
}

// ---------------------------------------------------------------------------
// K3: fp16 single-pass output projection: out[8192][256] = ocf x Wof^T + bo.
// ---------------------------------------------------------------------------
__global__ __launch_bounds__(256) void gemm_out_f16(
    const ushort* __restrict__ A, const ushort* __restrict__ Bw,
    const float* __restrict__ bias, float* __restrict__ fo)
{
    __shared__ __align__(16) ushort Ah[128 * 64];
    __shared__ __align__(16) ushort Bh[64 * 64];

    const int cpx = gridDim.x >> 3;
    const int wg  = (blockIdx.x & 7) * cpx + (blockIdx.x >> 3);
    const int m0 = (wg >> 2) * 128;
    const int n0 = (wg & 3) * 64;

    const int tid = threadIdx.x, w = tid >> 6, l = tid & 63;
    const int wr = w >> 1, wc = w & 1, g = l >> 4, c16 = l & 15;
    const int sr = l >> 3, sb = l & 7;

    f32x4 acc[4][2];
#pragma unroll
    for (int mi = 0; mi < 4; ++mi)
#pragma unroll
        for (int ni = 0; ni < 2; ++ni) acc[mi][ni] = (f32x4){0.f, 0.f, 0.f, 0.f};

    for (int k0 = 0; k0 < 2048; k0 += 64) {
        __syncthreads();
#pragma unroll
        for (int j = 0; j < 4; ++j) {
            const int rb = w * 32 + j * 8;
            const int r  = rb + sr;
            const size_t src = (size_t)(m0 + r) * 2048 + k0 + ((sb ^ (r & 7)) * 8);
            __builtin_amdgcn_global_load_lds(A + src, &Ah[rb * 64], 16, 0, 0);
        }
#pragma unroll
        for (int j = 0; j < 2; ++j) {
            const int rb = w * 16 + j * 8;
            const int r  = rb + sr;
            const size_t src = (size_t)(n0 + r) * 2048 + k0 + ((sb ^ (r & 7)) * 8);
            __builtin_amdgcn_global_load_lds(Bw + src, &Bh[rb * 64], 16, 0, 0);
        }
        asm volatile("s_waitcnt vmcnt(0)" ::: "memory");
        __syncthreads();

#pragma unroll
        for (int kh = 0; kh < 2; ++kh) {
            const int bsel = ((kh << 2) | g) ^ (c16 & 7);
            half8 af[4], bf[2];
#pragma unroll
            for (int mi = 0; mi < 4; ++mi)
                af[mi] = *(const half8*)&Ah[(wr * 64 + mi * 16 + c16) * 64 + bsel * 8];
#pragma unroll
            for (int ni = 0; ni < 2; ++ni)
                bf[ni] = *(const half8*)&Bh[(wc * 32 + ni * 16 + c16) * 64 + bsel * 8];
#pragma unroll
            for (int mi = 0; mi < 4; ++mi)
#pragma unroll
                for (int ni = 0; ni < 2; ++ni)
                    acc[mi][ni] = __builtin_amdgcn_mfma_f32_16x16x32_f16(af[mi], bf[ni], acc[mi][ni], 0, 0, 0);
        }
    }

#pragma unroll
    for (int mi = 0; mi < 4; ++mi)
#pragma unroll
        for (int ni = 0; ni < 2; ++ni) {
            const int n = n0 + wc * 32 + ni * 16 + c16;
            const float bb = bias[n];
#pragma unroll
            for (int j = 0; j < 4; ++j) {
                const int m = m0 + wr * 64 + mi * 16 + 4 * g + j;
                fo[(size_t)m * 256 + n] = acc[mi][ni][j] + bb;
            }
        }
}

// ---------------------------------------------------------------------------
// K2: fp16 MFMA flash attention — occupancy build (unchanged from R10).
// 16 q-rows/wave, LDS 52KB, 3 blocks/CU target, 1024 blocks heavy-first.
// ---------------------------------------------------------------------------
__global__ __launch_bounds__(256, 3) void flash_mfma(
    const ushort* __restrict__ qf, const ushort* __restrict__ kf,
    const ushort* __restrict__ vt, ushort* __restrict__ ocf)
{
    __shared__ __align__(16) ushort Ks[2][32 * 256];
    __shared__ __align__(16) ushort VTs[256 * 32];
    __shared__ __align__(16) ushort Pls[4][512];

    const int bid = blockIdx.x;
    const int idx = bid >> 3;
    const int hb  = (bid & 7) * 8 + (idx & 7);   // same-XCD hb groups
    const int qst = 15 - (idx >> 3);             // heavy-first
    const int h = hb >> 3, b = hb & 7;

    const int tid = threadIdx.x;
    const int w = tid >> 6, l = tid & 63;
    const int g = l >> 4, c16 = l & 15;
    const size_t qk_base = (size_t)h * QE + (size_t)b * (SEQ * EMBED);
    const size_t vt_base = (size_t)h * QE + (size_t)b * SEQ;

    const int psw = (c16 >> 1) & 3;
    const int rsw = c16 & 7;
    const int qw0 = qst * 64 + w * 16;
    const int q0 = qw0 + c16;

    half8 qfr[8];
    {
        const ushort* qr = qf + qk_base + (size_t)q0 * EMBED + g * 8;
#pragma unroll
        for (int kc = 0; kc < 8; ++kc)
            qfr[kc] = *(const half8*)(qr + kc * 32);
    }

    const ushort* kbase = kf + qk_base;
    const ushort* vbase = vt + vt_base;
    const int krow_l = l >> 5, kblk = l & 31;
    const int vd_l = l >> 2,  vblk = l & 3;
    uint koff[4], voff[4];
#pragma unroll
    for (int j = 0; j < 4; ++j) {
        const int row = 8 * w + 2 * j + krow_l;
        koff[j] = (uint)(row * EMBED + ((kblk ^ (row & 7)) * 8));
        const int d = w * 64 + j * 16 + vd_l;
        const int phi = ((d >> 1) ^ (d >> 3)) & 3;
        voff[j] = (uint)(d * NROWS + ((vblk ^ phi) * 8));
    }

    f32x4 acc[16];
#pragma unroll
    for (int dt = 0; dt < 16; ++dt) acc[dt] = (f32x4){0.f, 0.f, 0.f, 0.f};
    float m_r = -1e30f, l_p = 0.f;

    char* pw = (char*)&Pls[w][0];
    const int nkt = 2 * qst + 2;

#pragma unroll
    for (int j = 0; j < 4; ++j)
        __builtin_amdgcn_global_load_lds(kbase + koff[j], &Ks[0][(8 * w + 2 * j) * 256], 16, 0, 0);
    asm volatile("s_waitcnt vmcnt(0)" ::: "memory");
    __syncthreads();

    for (int kt = 0; kt < nkt; ++kt) {
#pragma unroll
        for (int j = 0; j < 4; ++j)
            __builtin_amdgcn_global_load_lds(vbase + voff[j] + kt * 32,
                                             &VTs[(w * 64 + j * 16) * 32], 16, 0, 0);
        if (kt + 1 < nkt) {
            const ushort* kb = kbase + (size_t)(kt + 1) * (32 * EMBED);
#pragma unroll
            for (int j = 0; j < 4; ++j)
                __builtin_amdgcn_global_load_lds(kb + koff[j],
                                                 &Ks[(kt + 1) & 1][(8 * w + 2 * j) * 256], 16, 0, 0);
        }

        const bool active = (kt * 32 <= qw0 + 15);
        if (active) {
            const ushort* Kb = &Ks[kt & 1][0];
            f32x4 s0 = (f32x4){0.f, 0.f, 0.f, 0.f};
            f32x4 s1 = (f32x4){0.f, 0.f, 0.f, 0.f};
#pragma unroll
            for (int kc = 0; kc < 8; ++kc) {
                const int blk = ((kc * 4 + g) ^ rsw) * 8;
                const half8 a0 = *(const half8*)&Kb[c16 * 256 + blk];
                const half8 a1 = *(const half8*)&Kb[(c16 + 16) * 256 + blk];
                s0 = __builtin_amdgcn_mfma_f32_16x16x32_f16(a0, qfr[kc], s0, 0, 0, 0);
                s1 = __builtin_amdgcn_mfma_f32_16x16x32_f16(a1, qfr[kc], s1, 0, 0, 0);
            }
            const int k0b = kt * 32 + 4 * g;
            float p0[4], p1[4];
            float pm = -1e30f;
#pragma unroll
            for (int r = 0; r < 4; ++r) {
                p0[r] = (k0b + r      > q0) ? -1e30f : s0[r];
                p1[r] = (k0b + 16 + r > q0) ? -1e30f : s1[r];
                pm = fmaxf(pm, fmaxf(p0[r], p1[r]));
            }
            if (__any(pm > m_r + 8.f)) {
                float gm = fmaxf(pm, __shfl_xor(pm, 16));
                gm = fmaxf(gm, __shfl_xor(gm, 32));
                const float mn = fmaxf(m_r, gm);
                const float sc = __expf(m_r - mn);
                l_p *= sc;
#pragma unroll
                for (int dt = 0; dt < 16; ++dt) acc[dt] *= sc;
                m_r = mn;
            }
#pragma unroll
            for (int r = 0; r < 4; ++r) {
                p0[r] = __expf(p0[r] - m_r);
                p1[r] = __expf(p1[r] - m_r);
                l_p += p0[r] + p1[r];
            }
#pragma unroll
            for (int t = 0; t < 2; ++t)
#pragma unroll
                for (int u = 0; u < 2; ++u) {
                    const int kk = 16 * t + 4 * g + 2 * u;
                    const int off = c16 * 64 + (((kk >> 3) ^ psw) * 16) + (kk & 7) * 2;
                    const float lo = t ? p1[2 * u] : p0[2 * u];
                    const float hi = t ? p1[2 * u + 1] : p0[2 * u + 1];
                    *(uint*)(pw + off) = (uint)f2h(lo) | ((uint)f2h(hi) << 16);
                }
        }

        asm volatile("s_waitcnt vmcnt(0)" ::: "memory");
        __syncthreads();

        if (active) {
            const half8 pfrag = *(const half8*)(pw + c16 * 64 + ((g ^ psw) * 16));
#pragma unroll
            for (int dt = 0; dt < 16; ++dt) {
                const int d = dt * 16 + c16;
                const int phi = ((d >> 1) ^ (d >> 3)) & 3;
                const half8 va = *(const half8*)&VTs[d * 32 + ((g ^ phi) * 8)];
                acc[dt] = __builtin_amdgcn_mfma_f32_16x16x32_f16(va, pfrag, acc[dt], 0, 0, 0);
            }
        }
        __syncthreads();
    }

    l_p += __shfl_xor(l_p, 16);
    l_p += __shfl_xor(l_p, 32);
    const float inv = 1.f / l_p;
    ushort* orow = ocf + ((size_t)(b * SEQ) + q0) * (HEADS * EMBED) + h * EMBED;
#pragma unroll
    for (int dt = 0; dt < 16; ++dt) {
        const f32x4 o = acc[dt] * inv;
        uint2 P2;
        P2.x = (uint)f2h(o[0]) | ((uint)f2h(o[1]) << 16);
        P2.y = (uint)f2h(o[2]) | ((uint)f2h(o[3]) << 16);
        *(uint2*)(orow + dt * 16 + 4 * g) = P2;
    }
}

extern "C" void kernel_launch(void* const* d_in, const int* in_sizes, int n_in,
                              void* d_out, int out_size, void* d_ws, size_t ws_size,
                              hipStream_t stream) {
    const float* X  = (const float*)d_in[0];
    const float* Wq = (const float*)d_in[1];
    const float* Wk = (const float*)d_in[2];
    const float* Wv = (const float*)d_in[3];
    const float* Wo = (const float*)d_in[4];
    const float* bo = (const float*)d_in[5];

    ushort* ws16 = (ushort*)d_ws;
    ushort* qf   = ws16;                     // [8][8192][256] fp16
    ushort* kf   = ws16 +  8 * QE;           // fp16
    ushort* vtb  = ws16 + 16 * QE;           // [8][256][8192] fp16
    ushort* ocf  = ws16 + 24 * QE;           // [8192][2048] fp16
    ushort* ex   = ws16 + 32 * QE;
    ushort* Xf   = ex;                       // 2M fp16
    ushort* Wqkf = ex + 2097152;             // [4096][256] fp16
    ushort* Wvf  = ex + 2097152 + 1048576;   // [2048][256] fp16
    ushort* Wof  = ex + 2097152 + 1048576 + 524288;   // [256][2048] fp16
    float*  out  = (float*)d_out;

    convert_f16<<<4096, 256, 0, stream>>>(X, Wq, Wk, Wv, Wo, Xf, Wqkf, Wvf, Wof);

    // merged QK + VT projection (qk: 2048 blocks, vt: 1024 blocks)
    gemm_qkvt<<<3072, 256, 0, stream>>>(Xf, Wqkf, Wvf, qf, kf, vtb);

    flash_mfma<<<1024, 256, 0, stream>>>(qf, kf, vtb, ocf);

    gemm_out_f16<<<256, 256, 0, stream>>>(ocf, Wof, bo, out);
}

// Round 12
// 136.411 us; speedup vs baseline: 2.1112x; 1.0367x over previous
//
#include <hip/hip_runtime.h>
#include <hip/hip_bf16.h>

#define EMBED 256
#define HEADS 8
#define BATCH 8
#define SEQ   1024
#define NROWS 8192

typedef __attribute__((ext_vector_type(8))) _Float16 half8;   // 8 fp16
typedef __attribute__((ext_vector_type(4))) float f32x4;
typedef unsigned int  uint;
typedef unsigned short ushort;

#define QE   ((size_t)2097152)   /* per-head elems: 8192*256 */

__device__ __forceinline__ ushort f2h(float f) {
    union { _Float16 h; ushort u; } cv; cv.h = (_Float16)f; return cv.u;
}

// ---------------------------------------------------------------------------
// K0: fp32 -> fp16 convert for X and all weights, one launch.
// ---------------------------------------------------------------------------
__global__ __launch_bounds__(256) void convert_f16(
    const float* __restrict__ X,  const float* __restrict__ Wq,
    const float* __restrict__ Wk, const float* __restrict__ Wv,
    const float* __restrict__ Wo,
    ushort* __restrict__ Xf, ushort* __restrict__ Wqkf,
    ushort* __restrict__ Wvf, ushort* __restrict__ Wof)
{
    const int blk = blockIdx.x;
    const float* src; ushort* dst; int i;
    if (blk < 2048)      { src = X;  dst = Xf;            i = blk * 256 + threadIdx.x; }
    else if (blk < 2560) { src = Wq; dst = Wqkf;          i = (blk - 2048) * 256 + threadIdx.x; }
    else if (blk < 3072) { src = Wk; dst = Wqkf + 524288; i = (blk - 2560) * 256 + threadIdx.x; }
    else if (blk < 3584) { src = Wv; dst = Wvf;           i = (blk - 3072) * 256 + threadIdx.x; }
    else                 { src = Wo; dst = Wof;           i = (blk - 3584) * 256 + threadIdx.x; }
    const float4 v = ((const float4*)src)[i];
    uint2 P;
    P.x = (uint)f2h(v.x) | ((uint)f2h(v.y) << 16);
    P.y = (uint)f2h(v.z) | ((uint)f2h(v.w) << 16);
    ((uint2*)dst)[i] = P;
}

// ---------------------------------------------------------------------------
// Single-pass fp16 MFMA GEMM core (NT): BM=BN=128, BK=64, KD=256,
// 256 threads = 4 waves (2x2). mode 0: q/k write; mode 1: vt write.
// ---------------------------------------------------------------------------
__device__ __forceinline__ void gemm1p_core(
    const ushort* __restrict__ Ag, const ushort* __restrict__ Bg,
    ushort* __restrict__ o0, ushort* __restrict__ o1,
    ushort* Ah, ushort* Bh, int wg, int Ntiles, int mode)
{
    const int m0 = (wg / Ntiles) * 128;
    const int n0 = (wg % Ntiles) * 128;

    const int tid = threadIdx.x, w = tid >> 6, l = tid & 63;
    const int wr = w >> 1, wc = w & 1, g = l >> 4, c16 = l & 15;
    const int sr = l >> 3, sb = l & 7;

    f32x4 acc[4][4];
#pragma unroll
    for (int mi = 0; mi < 4; ++mi)
#pragma unroll
        for (int ni = 0; ni < 4; ++ni) acc[mi][ni] = (f32x4){0.f, 0.f, 0.f, 0.f};

    for (int k0 = 0; k0 < 256; k0 += 64) {
        __syncthreads();
#pragma unroll
        for (int j = 0; j < 4; ++j) {
            const int rb = w * 32 + j * 8;
            const int r  = rb + sr;
            const size_t srcA = (size_t)(m0 + r) * 256 + k0 + ((sb ^ (r & 7)) * 8);
            __builtin_amdgcn_global_load_lds(Ag + srcA, &Ah[rb * 64], 16, 0, 0);
            const size_t srcB = (size_t)(n0 + r) * 256 + k0 + ((sb ^ (r & 7)) * 8);
            __builtin_amdgcn_global_load_lds(Bg + srcB, &Bh[rb * 64], 16, 0, 0);
        }
        asm volatile("s_waitcnt vmcnt(0)" ::: "memory");
        __syncthreads();

#pragma unroll
        for (int kh = 0; kh < 2; ++kh) {
            const int bsel = ((kh << 2) | g) ^ (c16 & 7);
            half8 af[4], bf[4];
#pragma unroll
            for (int mi = 0; mi < 4; ++mi)
                af[mi] = *(const half8*)&Ah[(wr * 64 + mi * 16 + c16) * 64 + bsel * 8];
#pragma unroll
            for (int ni = 0; ni < 4; ++ni)
                bf[ni] = *(const half8*)&Bh[(wc * 64 + ni * 16 + c16) * 64 + bsel * 8];
#pragma unroll
            for (int mi = 0; mi < 4; ++mi)
#pragma unroll
                for (int ni = 0; ni < 4; ++ni)
                    acc[mi][ni] = __builtin_amdgcn_mfma_f32_16x16x32_f16(af[mi], bf[ni], acc[mi][ni], 0, 0, 0);
        }
    }

#pragma unroll
    for (int mi = 0; mi < 4; ++mi)
#pragma unroll
        for (int ni = 0; ni < 4; ++ni) {
            const int n = n0 + wc * 64 + ni * 16 + c16;
            if (mode == 0) {
                const int op = n >> 11, hh = (n >> 8) & 7, d = n & 255;
                ushort* tq = (op ? o1 : o0) + (size_t)hh * QE + d;
#pragma unroll
                for (int j = 0; j < 4; ++j) {
                    const int m = m0 + wr * 64 + mi * 16 + 4 * g + j;
                    tq[(size_t)m * 256] = f2h(acc[mi][ni][j]);
                }
            } else {
#pragma unroll
                for (int j = 0; j < 4; ++j) {
                    const int m = m0 + wr * 64 + mi * 16 + 4 * g + j;
                    o0[(size_t)m * NROWS + n] = f2h(acc[mi][ni][j]);
                }
            }
        }
}

// Merged QK + VT projection launch: bid<2048 -> qk GEMM, else vt GEMM.
__global__ __launch_bounds__(256) void gemm_qkvt(
    const ushort* __restrict__ Xf,
    const ushort* __restrict__ Wqkf, const ushort* __restrict__ Wvf,
    ushort* __restrict__ qf, ushort* __restrict__ kf, ushort* __restrict__ vtb)
{
    __shared__ __align__(16) ushort Ah[128 * 64];
    __shared__ __align__(16) ushort Bh[128 * 64];
    const int bid = blockIdx.x;
    if (bid < 2048) {
        const int wg = (bid & 7) * 256 + (bid >> 3);
        gemm1p_core(Xf, Wqkf, qf, kf, Ah, Bh, wg, 32, 0);
    } else {
        const int b2 = bid - 2048;
        const int wg = (b2 & 7) * 128 + (b2 >> 3);
        gemm1p_core(Wvf, Xf, vtb, nullptr, Ah, Bh, wg, 64, 1);
    }
}

// ---------------------------------------------------------------------------
// K3: fp16 output projection, BM=64 x BN=64 -> 512 blocks (was 256: 1/CU,
// latency-exposed). out[8192][256] = ocf x Wof^T + bo. LDS 16KB.
// ---------------------------------------------------------------------------
__global__ __launch_bounds__(256) void gemm_out_f16(
    const ushort* __restrict__ A, const ushort* __restrict__ Bw,
    const float* __restrict__ bias, float* __restrict__ fo)
{
    __shared__ __align__(16) ushort Ah[64 * 64];
    __shared__ __align__(16) ushort Bh[64 * 64];

    const int wg = (blockIdx.x & 7) * 64 + (blockIdx.x >> 3);
    const int m0 = (wg >> 2) * 64;
    const int n0 = (wg & 3) * 64;

    const int tid = threadIdx.x, w = tid >> 6, l = tid & 63;
    const int wr = w >> 1, wc = w & 1, g = l >> 4, c16 = l & 15;
    const int sr = l >> 3, sb = l & 7;

    f32x4 acc[2][2];
#pragma unroll
    for (int mi = 0; mi < 2; ++mi)
#pragma unroll
        for (int ni = 0; ni < 2; ++ni) acc[mi][ni] = (f32x4){0.f, 0.f, 0.f, 0.f};

    for (int k0 = 0; k0 < 2048; k0 += 64) {
        __syncthreads();
#pragma unroll
        for (int j = 0; j < 2; ++j) {
            const int rb = w * 16 + j * 8;
            const int r  = rb + sr;
            const size_t srcA = (size_t)(m0 + r) * 2048 + k0 + ((sb ^ (r & 7)) * 8);
            __builtin_amdgcn_global_load_lds(A + srcA, &Ah[rb * 64], 16, 0, 0);
            const size_t srcB = (size_t)(n0 + r) * 2048 + k0 + ((sb ^ (r & 7)) * 8);
            __builtin_amdgcn_global_load_lds(Bw + srcB, &Bh[rb * 64], 16, 0, 0);
        }
        asm volatile("s_waitcnt vmcnt(0)" ::: "memory");
        __syncthreads();

#pragma unroll
        for (int kh = 0; kh < 2; ++kh) {
            const int bsel = ((kh << 2) | g) ^ (c16 & 7);
            half8 af[2], bf[2];
#pragma unroll
            for (int mi = 0; mi < 2; ++mi)
                af[mi] = *(const half8*)&Ah[(wr * 32 + mi * 16 + c16) * 64 + bsel * 8];
#pragma unroll
            for (int ni = 0; ni < 2; ++ni)
                bf[ni] = *(const half8*)&Bh[(wc * 32 + ni * 16 + c16) * 64 + bsel * 8];
#pragma unroll
            for (int mi = 0; mi < 2; ++mi)
#pragma unroll
                for (int ni = 0; ni < 2; ++ni)
                    acc[mi][ni] = __builtin_amdgcn_mfma_f32_16x16x32_f16(af[mi], bf[ni], acc[mi][ni], 0, 0, 0);
        }
    }

#pragma unroll
    for (int mi = 0; mi < 2; ++mi)
#pragma unroll
        for (int ni = 0; ni < 2; ++ni) {
            const int n = n0 + wc * 32 + ni * 16 + c16;
            const float bb = bias[n];
#pragma unroll
            for (int j = 0; j < 4; ++j) {
                const int m = m0 + wr * 32 + mi * 16 + 4 * g + j;
                fo[(size_t)m * 256 + n] = acc[mi][ni][j] + bb;
            }
        }
}

// ---------------------------------------------------------------------------
// K2: fp16 MFMA flash attention — counted-vmcnt build (T4).
// 16 q-rows/wave, LDS 52KB, 1024 blocks heavy-first, hb pinned per XCD.
// Raw s_barrier + counted vmcnt: barrier1 waits own-VT only (vmcnt(4),
// K[kt+1] stays in flight); barrier2 waits vmcnt(0) (K landed during PV).
// QK needs no wait (K[kt] drained at previous barrier2). Cross-wave safety:
// each wave waits its OWN loads before the joining barrier.
// ---------------------------------------------------------------------------
__global__ __launch_bounds__(256, 3) void flash_mfma(
    const ushort* __restrict__ qf, const ushort* __restrict__ kf,
    const ushort* __restrict__ vt, ushort* __restrict__ ocf)
{
    __shared__ __align__(16) ushort Ks[2][32 * 256];
    __shared__ __align__(16) ushort VTs[256 * 32];
    __shared__ __align__(16) ushort Pls[4][512];

    const int bid = blockIdx.x;
    const int idx = bid >> 3;
    const int hb  = (bid & 7) * 8 + (idx & 7);   // same-XCD hb groups
    const int qst = 15 - (idx >> 3);             // heavy-first
    const int h = hb >> 3, b = hb & 7;

    const int tid = threadIdx.x;
    const int w = tid >> 6, l = tid & 63;
    const int g = l >> 4, c16 = l & 15;
    const size_t qk_base = (size_t)h * QE + (size_t)b * (SEQ * EMBED);
    const size_t vt_base = (size_t)h * QE + (size_t)b * SEQ;

    const int psw = (c16 >> 1) & 3;
    const int rsw = c16 & 7;
    const int qw0 = qst * 64 + w * 16;
    const int q0 = qw0 + c16;

    half8 qfr[8];
    {
        const ushort* qr = qf + qk_base + (size_t)q0 * EMBED + g * 8;
#pragma unroll
        for (int kc = 0; kc < 8; ++kc)
            qfr[kc] = *(const half8*)(qr + kc * 32);
    }

    const ushort* kbase = kf + qk_base;
    const ushort* vbase = vt + vt_base;
    const int krow_l = l >> 5, kblk = l & 31;
    const int vd_l = l >> 2,  vblk = l & 3;
    uint koff[4], voff[4];
#pragma unroll
    for (int j = 0; j < 4; ++j) {
        const int row = 8 * w + 2 * j + krow_l;
        koff[j] = (uint)(row * EMBED + ((kblk ^ (row & 7)) * 8));
        const int d = w * 64 + j * 16 + vd_l;
        const int phi = ((d >> 1) ^ (d >> 3)) & 3;
        voff[j] = (uint)(d * NROWS + ((vblk ^ phi) * 8));
    }

    f32x4 acc[16];
#pragma unroll
    for (int dt = 0; dt < 16; ++dt) acc[dt] = (f32x4){0.f, 0.f, 0.f, 0.f};
    float m_r = -1e30f, l_p = 0.f;

    char* pw = (char*)&Pls[w][0];
    const int nkt = 2 * qst + 2;

    // prologue: stage K[0]
#pragma unroll
    for (int j = 0; j < 4; ++j)
        __builtin_amdgcn_global_load_lds(kbase + koff[j], &Ks[0][(8 * w + 2 * j) * 256], 16, 0, 0);
    asm volatile("s_waitcnt vmcnt(0)" ::: "memory");
    __builtin_amdgcn_s_barrier();
    __builtin_amdgcn_sched_barrier(0);

    for (int kt = 0; kt < nkt; ++kt) {
        // issue VT[kt] FIRST (oldest in queue -> covered by vmcnt(4)),
        // then K[kt+1] (covered by barrier2's vmcnt(0)).
#pragma unroll
        for (int j = 0; j < 4; ++j)
            __builtin_amdgcn_global_load_lds(vbase + voff[j] + kt * 32,
                                             &VTs[(w * 64 + j * 16) * 32], 16, 0, 0);
        const bool havek = (kt + 1 < nkt);
        if (havek) {
            const ushort* kb = kbase + (size_t)(kt + 1) * (32 * EMBED);
#pragma unroll
            for (int j = 0; j < 4; ++j)
                __builtin_amdgcn_global_load_lds(kb + koff[j],
                                                 &Ks[(kt + 1) & 1][(8 * w + 2 * j) * 256], 16, 0, 0);
        }

        const bool active = (kt * 32 <= qw0 + 15);
        if (active) {
            // ---- QK^T on K[kt] (already complete from previous barrier2) ----
            const ushort* Kb = &Ks[kt & 1][0];
            f32x4 s0 = (f32x4){0.f, 0.f, 0.f, 0.f};
            f32x4 s1 = (f32x4){0.f, 0.f, 0.f, 0.f};
#pragma unroll
            for (int kc = 0; kc < 8; ++kc) {
                const int blk = ((kc * 4 + g) ^ rsw) * 8;
                const half8 a0 = *(const half8*)&Kb[c16 * 256 + blk];
                const half8 a1 = *(const half8*)&Kb[(c16 + 16) * 256 + blk];
                s0 = __builtin_amdgcn_mfma_f32_16x16x32_f16(a0, qfr[kc], s0, 0, 0, 0);
                s1 = __builtin_amdgcn_mfma_f32_16x16x32_f16(a1, qfr[kc], s1, 0, 0, 0);
            }
            const int k0b = kt * 32 + 4 * g;
            float p0[4], p1[4];
            float pm = -1e30f;
#pragma unroll
            for (int r = 0; r < 4; ++r) {
                p0[r] = (k0b + r      > q0) ? -1e30f : s0[r];
                p1[r] = (k0b + 16 + r > q0) ? -1e30f : s1[r];
                pm = fmaxf(pm, fmaxf(p0[r], p1[r]));
            }
            if (__any(pm > m_r + 8.f)) {
                float gm = fmaxf(pm, __shfl_xor(pm, 16));
                gm = fmaxf(gm, __shfl_xor(gm, 32));
                const float mn = fmaxf(m_r, gm);
                const float sc = __expf(m_r - mn);
                l_p *= sc;
#pragma unroll
                for (int dt = 0; dt < 16; ++dt) acc[dt] *= sc;
                m_r = mn;
            }
#pragma unroll
            for (int r = 0; r < 4; ++r) {
                p0[r] = __expf(p0[r] - m_r);
                p1[r] = __expf(p1[r] - m_r);
                l_p += p0[r] + p1[r];
            }
#pragma unroll
            for (int t = 0; t < 2; ++t)
#pragma unroll
                for (int u = 0; u < 2; ++u) {
                    const int kk = 16 * t + 4 * g + 2 * u;
                    const int off = c16 * 64 + (((kk >> 3) ^ psw) * 16) + (kk & 7) * 2;
                    const float lo = t ? p1[2 * u] : p0[2 * u];
                    const float hi = t ? p1[2 * u + 1] : p0[2 * u + 1];
                    *(uint*)(pw + off) = (uint)f2h(lo) | ((uint)f2h(hi) << 16);
                }
        }

        // barrier1: own VT landed (K[kt+1] stays in flight when havek)
        if (havek) asm volatile("s_waitcnt vmcnt(4)" ::: "memory");
        else       asm volatile("s_waitcnt vmcnt(0)" ::: "memory");
        __builtin_amdgcn_s_barrier();
        __builtin_amdgcn_sched_barrier(0);

        if (active) {
            const half8 pfrag = *(const half8*)(pw + c16 * 64 + ((g ^ psw) * 16));
#pragma unroll
            for (int dt = 0; dt < 16; ++dt) {
                const int d = dt * 16 + c16;
                const int phi = ((d >> 1) ^ (d >> 3)) & 3;
                const half8 va = *(const half8*)&VTs[d * 32 + ((g ^ phi) * 8)];
                acc[dt] = __builtin_amdgcn_mfma_f32_16x16x32_f16(va, pfrag, acc[dt], 0, 0, 0);
            }
        }

        // barrier2: own K[kt+1] landed; VT buffer free for next iter
        asm volatile("s_waitcnt vmcnt(0)" ::: "memory");
        __builtin_amdgcn_s_barrier();
        __builtin_amdgcn_sched_barrier(0);
    }

    l_p += __shfl_xor(l_p, 16);
    l_p += __shfl_xor(l_p, 32);
    const float inv = 1.f / l_p;
    ushort* orow = ocf + ((size_t)(b * SEQ) + q0) * (HEADS * EMBED) + h * EMBED;
#pragma unroll
    for (int dt = 0; dt < 16; ++dt) {
        const f32x4 o = acc[dt] * inv;
        uint2 P2;
        P2.x = (uint)f2h(o[0]) | ((uint)f2h(o[1]) << 16);
        P2.y = (uint)f2h(o[2]) | ((uint)f2h(o[3]) << 16);
        *(uint2*)(orow + dt * 16 + 4 * g) = P2;
    }
}

extern "C" void kernel_launch(void* const* d_in, const int* in_sizes, int n_in,
                              void* d_out, int out_size, void* d_ws, size_t ws_size,
                              hipStream_t stream) {
    const float* X  = (const float*)d_in[0];
    const float* Wq = (const float*)d_in[1];
    const float* Wk = (const float*)d_in[2];
    const float* Wv = (const float*)d_in[3];
    const float* Wo = (const float*)d_in[4];
    const float* bo = (const float*)d_in[5];

    ushort* ws16 = (ushort*)d_ws;
    ushort* qf   = ws16;                     // [8][8192][256] fp16
    ushort* kf   = ws16 +  8 * QE;           // fp16
    ushort* vtb  = ws16 + 16 * QE;           // [8][256][8192] fp16
    ushort* ocf  = ws16 + 24 * QE;           // [8192][2048] fp16
    ushort* ex   = ws16 + 32 * QE;
    ushort* Xf   = ex;                       // 2M fp16
    ushort* Wqkf = ex + 2097152;             // [4096][256] fp16
    ushort* Wvf  = ex + 2097152 + 1048576;   // [2048][256] fp16
    ushort* Wof  = ex + 2097152 + 1048576 + 524288;   // [256][2048] fp16
    float*  out  = (float*)d_out;

    convert_f16<<<4096, 256, 0, stream>>>(X, Wq, Wk, Wv, Wo, Xf, Wqkf, Wvf, Wof);

    gemm_qkvt<<<3072, 256, 0, stream>>>(Xf, Wqkf, Wvf, qf, kf, vtb);

    flash_mfma<<<1024, 256, 0, stream>>>(qf, kf, vtb, ocf);

    gemm_out_f16<<<512, 256, 0, stream>>>(ocf, Wof, bo, out);
}